// Round 11
// baseline (188.862 us; speedup 1.0000x reference)
//
#include <hip/hip_runtime.h>
#include <hip/hip_bf16.h>

typedef __attribute__((ext_vector_type(8))) short short8;     // 8 bf16 (MFMA A/B frag, K=32)
typedef __attribute__((ext_vector_type(4))) float float4v;    // MFMA C/D frag

#define VMC(N) do { asm volatile("s_waitcnt vmcnt(" #N ")" ::: "memory"); \
                    __builtin_amdgcn_sched_barrier(0); } while (0)
#define BAR()  do { __builtin_amdgcn_s_barrier(); \
                    __builtin_amdgcn_sched_barrier(0); } while (0)

// RoPE on an 8-elem bf16 chunk (4 pairs). tA/tB = tab[p..p+1], tab[p+2..p+3]
// as (cos,sin,cos,sin). Identical rounding chain to the old qkv_prep path.
__device__ inline short8 rope8(short8 raw, float4 tA, float4 tB, float scale) {
  float c[4] = {tA.x, tA.z, tB.x, tB.z};
  float s[4] = {tA.y, tA.w, tB.y, tB.w};
  union { short8 v; short e[8]; } in, out;
  in.v = raw;
  #pragma unroll
  for (int j = 0; j < 4; ++j) {
    __hip_bfloat16 h1 = *reinterpret_cast<__hip_bfloat16*>(&in.e[2 * j]);
    __hip_bfloat16 h2 = *reinterpret_cast<__hip_bfloat16*>(&in.e[2 * j + 1]);
    const float x1 = __bfloat162float(h1), x2 = __bfloat162float(h2);
    __hip_bfloat16 o1 = __float2bfloat16((x1 * c[j] - x2 * s[j]) * scale);
    __hip_bfloat16 o2 = __float2bfloat16((x1 * s[j] + x2 * c[j]) * scale);
    out.e[2 * j]     = *reinterpret_cast<short*>(&o1);
    out.e[2 * j + 1] = *reinterpret_cast<short*>(&o2);
  }
  return out.v;
}

// ---------------------------------------------------------------------------
// prep_all: all input prep in ONE launch (r25 form: packed transpose stores).
// ---------------------------------------------------------------------------
__global__ __launch_bounds__(256) void prep_all(
    const float* __restrict__ x, __hip_bfloat16* __restrict__ xb,
    float2* __restrict__ tab,
    const float* __restrict__ Wqkv, const float* __restrict__ Wout,
    __hip_bfloat16* __restrict__ WqkvT, __hip_bfloat16* __restrict__ WoutT) {
  __shared__ __hip_bfloat16 tile[32][33];
  const int id = blockIdx.x;
  if (id < 4096) {
    const int i = id * 256 + threadIdx.x;
    const float4 v = *(const float4*)(x + (size_t)i * 4);
    __hip_bfloat16 o[4];
    o[0] = __float2bfloat16(v.x); o[1] = __float2bfloat16(v.y);
    o[2] = __float2bfloat16(v.z); o[3] = __float2bfloat16(v.w);
    *(uint2*)(xb + (size_t)i * 4) = *(const uint2*)o;
    return;
  }
  if (id < 4352) {
    const int i = (id - 4096) * 256 + threadIdx.x;   // 65536
    const int s = i >> 5, p = i & 31;
    const float freq = powf(10000.f, -(float)(p * 2) / 64.f);
    float sn, cs;
    sincosf((float)s * freq, &sn, &cs);
    tab[i] = make_float2(cs, sn);
    return;
  }
  const float* in;
  __hip_bfloat16* out;
  int C, bx, by;
  if (id < 7424) {
    const int lid = id - 4352;
    in = Wqkv; out = WqkvT; C = 3072; bx = lid % 96; by = lid / 96;
  } else {
    const int lid = id - 7424;
    in = Wout; out = WoutT; C = 1024; bx = lid & 31; by = lid >> 5;
  }
  const int R = 1024;
  const int c0 = bx * 32, r0 = by * 32;
  const int tx = threadIdx.x & 31, ty = threadIdx.x >> 5;  // ty 0..7
  #pragma unroll
  for (int i = ty; i < 32; i += 8)
    tile[i][tx] = __float2bfloat16(in[(size_t)(r0 + i) * C + (c0 + tx)]);
  __syncthreads();
  const int sx = threadIdx.x & 15, sy = threadIdx.x >> 4;  // sy 0..15
  #pragma unroll
  for (int i = sy; i < 32; i += 16) {
    union { unsigned u; short e[2]; } pk;
    pk.e[0] = *reinterpret_cast<short*>(&tile[2 * sx][i]);
    pk.e[1] = *reinterpret_cast<short*>(&tile[2 * sx + 1][i]);
    *(unsigned*)&out[(size_t)(c0 + i) * R + r0 + 2 * sx] = pk.u;
  }
}

// ---------------------------------------------------------------------------
// gemm_bt: r6/r12 2-barrier structure — used for gemm2 only this round.
// ---------------------------------------------------------------------------
template <typename OutT, int BM, int BN>
__global__ __launch_bounds__(256) void gemm_bt(
    const __hip_bfloat16* __restrict__ A,
    const __hip_bfloat16* __restrict__ Bt,
    OutT* __restrict__ C,
    int M, int N, int K) {
  __shared__ __hip_bfloat16 lA[BM][64];
  __shared__ __hip_bfloat16 lB[BN][64];
  constexpr int NI = BM / 32, NJ = BN / 32;
  const int t = threadIdx.x;
  const int lane = t & 63, wave = t >> 6;
  const int quad = lane >> 4, ln = lane & 15;
  const int m0 = blockIdx.y * BM, n0 = blockIdx.x * BN;
  const int wm = (wave >> 1) * (BM / 2), wn = (wave & 1) * (BN / 2);
  const int srow = lane >> 3;
  const int schunk = ((lane & 7) ^ srow) * 8;

  float4v acc[NI][NJ];
  #pragma unroll
  for (int i = 0; i < NI; ++i)
    #pragma unroll
    for (int j = 0; j < NJ; ++j)
      acc[i][j] = (float4v){0.f, 0.f, 0.f, 0.f};

  for (int kt = 0; kt < K; kt += 64) {
    __syncthreads();
    #pragma unroll
    for (int g = 0; g < BM / 32; ++g) {
      const int rbase = wave * (BM / 4) + g * 8;
      __builtin_amdgcn_global_load_lds(
          (const __attribute__((address_space(1))) void*)
              (A + (size_t)(m0 + rbase + srow) * K + kt + schunk),
          (__attribute__((address_space(3))) void*)&lA[rbase][0], 16, 0, 0);
    }
    #pragma unroll
    for (int g = 0; g < BN / 32; ++g) {
      const int rbase = wave * (BN / 4) + g * 8;
      __builtin_amdgcn_global_load_lds(
          (const __attribute__((address_space(1))) void*)
              (Bt + (size_t)(n0 + rbase + srow) * K + kt + schunk),
          (__attribute__((address_space(3))) void*)&lB[rbase][0], 16, 0, 0);
    }
    __syncthreads();
    #pragma unroll
    for (int step = 0; step < 2; ++step) {
      short8 af[NI], bf[NJ];
      #pragma unroll
      for (int i = 0; i < NI; ++i)
        af[i] = *(const short8*)&lA[wm + i * 16 + ln][((step * 4 + quad) ^ (ln & 7)) * 8];
      #pragma unroll
      for (int j = 0; j < NJ; ++j)
        bf[j] = *(const short8*)&lB[wn + j * 16 + ln][((step * 4 + quad) ^ (ln & 7)) * 8];
      #pragma unroll
      for (int i = 0; i < NI; ++i)
        #pragma unroll
        for (int j = 0; j < NJ; ++j)
          acc[i][j] = __builtin_amdgcn_mfma_f32_16x16x32_bf16(af[i], bf[j], acc[i][j], 0, 0, 0);
    }
  }
  #pragma unroll
  for (int i = 0; i < NI; ++i)
    #pragma unroll
    for (int j = 0; j < NJ; ++j)
      #pragma unroll
      for (int r = 0; r < 4; ++r) {
        const int row = m0 + wm + i * 16 + quad * 4 + r;
        const int col = n0 + wn + j * 16 + ln;
        if constexpr (__is_same(OutT, float))
          C[(size_t)row * N + col] = acc[i][j][r];
        else
          C[(size_t)row * N + col] = __float2bfloat16(acc[i][j][r]);
      }
}

// ---------------------------------------------------------------------------
// gemm1_8p (r26): 256x256 tile, BK=64, 2-dbuf, 4 phases/tile with counted
// vmcnt — the m201-style per-phase interleave, derived with a provable
// retirement schedule (r22's coarse ring failed; m196: coarse split hurts).
//
// Tile t lives in buf[t&1]; phases = C-quadrants (m0n0),(m0n1),(m1n0),(m1n1).
// Region retirement (all waves, enforced by the phase barrier):
//   A-half0 (rows {0-63,128-191}) retired after ph2;  B-half0 (rows with
//   (r&63)<32) after ph3; A-half1/B-half1 at tile end.
// Staging (one half-tile = 2 gload/thread per phase, into retired regions):
//   ph1: A1(t+1) [buf^1, region retired at t-1 end]
//   ph2: B1(t+1) [buf^1, retired at t-1 end]
//   ph3: A0(t+2) [buf,  A-half0 retired at ph2 barrier]
//   ph4: B0(t+2) [buf,  B-half0 retired at ph3 barrier]
// Issue order fixed -> exact arrival gating: ph1 vmcnt(8) (needs A0/B0(t),
// 4 half-stages=8 loads issued after), ph2 vmcnt(6) (needs B1(t)); ph3/ph4
// free (covered by ph2's wait). Tail t=15: vmcnt(4)/vmcnt(0). vmcnt never
// drains to 0 mid-loop (T4). Collective safety: every wave issues the same
// load sequence, so per-wave vmcnt(N)+s_barrier => half-tile fully landed.
// Per phase: 4-12 ds_read_b128 || 2 gload || 16 MFMA w/ setprio (T5).
// LDS 128KiB, 8 waves (2Mx4N), per-wave C 128x64 = acc[8][4]. Grid 12x16.
// ---------------------------------------------------------------------------
__global__ __launch_bounds__(512, 1) void gemm1_8p(
    const __hip_bfloat16* __restrict__ A,     // xb    4096x1024
    const __hip_bfloat16* __restrict__ Bt,    // WqkvT 3072x1024
    __hip_bfloat16* __restrict__ C) {         // qkv   4096x3072
  constexpr int KD = 1024, NN = 3072, NT = 16;   // BK=64
  __shared__ __hip_bfloat16 lA[2][256][64];
  __shared__ __hip_bfloat16 lB[2][256][64];
  const int t = threadIdx.x;
  const int lane = t & 63, w = t >> 6;
  const int quad = lane >> 4, ln = lane & 15;
  const int m0 = blockIdx.y * 256, n0 = blockIdx.x * 256;
  const int wm = (w >> 2) * 128, wn = (w & 3) * 64;
  const int srow = t >> 3;                 // 0..63 (8 rows per 64-thread wave)
  const int dch = t & 7;                   // dest 16B chunk

  float4v acc[8][4];
  #pragma unroll
  for (int mq = 0; mq < 8; ++mq)
    #pragma unroll
    for (int nq = 0; nq < 4; ++nq)
      acc[mq][nq] = (float4v){0.f, 0.f, 0.f, 0.f};

  // A-half h = rows {h*64..h*64+63, 128+h*64..}; per-lane dest is linear
  // (elem off = lane*8 within each gload) — required by global_load_lds.
  auto stageA = [&](int buf, int tile, int half) {
    #pragma unroll
    for (int g = 0; g < 2; ++g) {
      const int row = g * 128 + half * 64 + srow;
      const int gch = dch ^ (row & 7);     // pre-swizzled source chunk
      __builtin_amdgcn_global_load_lds(
          (const __attribute__((address_space(1))) void*)
              (A + (size_t)(m0 + row) * KD + tile * 64 + gch * 8),
          (__attribute__((address_space(3))) void*)&lA[buf][row][dch * 8], 16, 0, 0);
    }
  };
  // B-half h = rows with (r&63) in [h*32, h*32+32)
  auto stageB = [&](int buf, int tile, int half) {
    #pragma unroll
    for (int g = 0; g < 2; ++g) {
      const int row = g * 128 + half * 32 + (srow & 31) + (srow >> 5) * 64;
      const int gch = dch ^ (row & 7);
      __builtin_amdgcn_global_load_lds(
          (const __attribute__((address_space(1))) void*)
              (Bt + (size_t)(n0 + row) * KD + tile * 64 + gch * 8),
          (__attribute__((address_space(3))) void*)&lB[buf][row][dch * 8], 16, 0, 0);
    }
  };

  short8 af[4][2];                         // A-frags, reused across n-phases
  auto loadA = [&](int buf, int ms) {
    #pragma unroll
    for (int mq = 0; mq < 4; ++mq) {
      const int r = wm + ms * 64 + mq * 16 + ln;
      #pragma unroll
      for (int s = 0; s < 2; ++s)
        af[mq][s] = *(const short8*)&lA[buf][r][((s * 4 + quad) ^ (r & 7)) * 8];
    }
  };
  auto phase = [&](int buf, int ms, int ns) {
    short8 bf[2][2];
    #pragma unroll
    for (int nq = 0; nq < 2; ++nq) {
      const int r = wn + ns * 32 + nq * 16 + ln;
      #pragma unroll
      for (int s = 0; s < 2; ++s)
        bf[nq][s] = *(const short8*)&lB[buf][r][((s * 4 + quad) ^ (r & 7)) * 8];
    }
    __builtin_amdgcn_s_setprio(1);
    #pragma unroll
    for (int s = 0; s < 2; ++s)
      #pragma unroll
      for (int mq = 0; mq < 4; ++mq)
        #pragma unroll
        for (int nq = 0; nq < 2; ++nq)
          acc[ms * 4 + mq][ns * 2 + nq] = __builtin_amdgcn_mfma_f32_16x16x32_bf16(
              af[mq][s], bf[nq][s], acc[ms * 4 + mq][ns * 2 + nq], 0, 0, 0);
    __builtin_amdgcn_s_setprio(0);
  };

  // Prologue issue order: A0(0),B0(0),A1(0),B1(0),A0(1),B0(1)  [12 loads]
  stageA(0, 0, 0); stageB(0, 0, 0); stageA(0, 0, 1); stageB(0, 0, 1);
  stageA(1, 1, 0); stageB(1, 1, 0);

  for (int tile = 0; tile < NT; ++tile) {
    const int buf = tile & 1;
    // ---- ph1 (m0,n0)
    if (tile < NT - 1) VMC(8); else VMC(4);
    BAR();
    if (tile + 1 < NT) stageA(buf ^ 1, tile + 1, 1);
    loadA(buf, 0);
    phase(buf, 0, 0);
    // ---- ph2 (m0,n1)
    if (tile < NT - 1) VMC(6); else VMC(0);
    BAR();
    if (tile + 1 < NT) stageB(buf ^ 1, tile + 1, 1);
    phase(buf, 0, 1);
    // ---- ph3 (m1,n0)
    BAR();
    if (tile + 2 < NT) stageA(buf, tile + 2, 0);
    loadA(buf, 1);
    phase(buf, 1, 0);
    // ---- ph4 (m1,n1)
    BAR();
    if (tile + 2 < NT) stageB(buf, tile + 2, 0);
    phase(buf, 1, 1);
  }

  #pragma unroll
  for (int am = 0; am < 8; ++am)
    #pragma unroll
    for (int an = 0; an < 4; ++an)
      #pragma unroll
      for (int r = 0; r < 4; ++r) {
        const int row = m0 + wm + (am >> 2) * 64 + (am & 3) * 16 + quad * 4 + r;
        const int col = n0 + wn + (an >> 1) * 32 + (an & 1) * 16 + ln;
        C[(size_t)row * NN + col] = __float2bfloat16(acc[am][an][r]);
      }
}

// ---------------------------------------------------------------------------
// qkv_prep r25: K RoPE (vectorized 16B) + V transpose (8B both sides).
// ---------------------------------------------------------------------------
__global__ __launch_bounds__(256) void qkv_prep(
    const __hip_bfloat16* __restrict__ qkv,
    const float2* __restrict__ tab,
    __hip_bfloat16* __restrict__ K,
    __hip_bfloat16* __restrict__ Vt) {
  __shared__ __hip_bfloat16 tile[64][68];     // +4 pad: 8B-aligned rows
  const int s0 = blockIdx.x * 64;
  const int bh = blockIdx.y;
  const int h = bh & 15, b = bh >> 4;
  const int t = threadIdx.x;

  const int dd = (t & 7) * 8;
  const int sl = t >> 3;                      // 0..31
  #pragma unroll
  for (int ss = sl; ss < 64; ss += 32) {
    const int s = s0 + ss;
    short8 kv = *(const short8*)&qkv[(size_t)(b * 2048 + s) * 3072 + 1024 + h * 64 + dd];
    const float4 tA = *(const float4*)&tab[(size_t)s * 32 + (dd >> 1)];
    const float4 tB = *(const float4*)&tab[(size_t)s * 32 + (dd >> 1) + 2];
    *(short8*)&K[((size_t)bh * 2048 + s) * 64 + dd] = rope8(kv, tA, tB, 1.0f);
  }

  const int dgrp = (t & 15) * 4;              // d base for load
  const int srow = t >> 4;                    // 0..15
  #pragma unroll
  for (int i = srow; i < 64; i += 16) {
    ushort4 v4 = *(const ushort4*)&qkv[(size_t)(b * 2048 + s0 + i) * 3072 + 2048 + h * 64 + dgrp];
    *(ushort4*)&tile[i][dgrp] = v4;
  }
  __syncthreads();
  const int vx = t & 15, vy = t >> 4;         // vx -> s-quad, vy -> d
  #pragma unroll
  for (int d = vy; d < 64; d += 16) {
    union { ushort4 v; short e[4]; } pk;
    #pragma unroll
    for (int jj = 0; jj < 4; ++jj)
      pk.e[jj] = *reinterpret_cast<short*>(&tile[4 * vx + jj][d]);
    *(ushort4*)&Vt[((size_t)bh * 64 + d) * 2048 + s0 + 4 * vx] = pk.v;
  }
}

// ---------------------------------------------------------------------------
// Flash-style causal attention — r25 form (swapped-operand QK, in-register P,
// f-swizzle lK, fused RoPE-Q, packed lO epilogue). Unchanged.
// ---------------------------------------------------------------------------
__global__ __launch_bounds__(256) void attention(
    const __hip_bfloat16* __restrict__ qkv,
    const float2* __restrict__ tab,
    const __hip_bfloat16* __restrict__ K,
    const __hip_bfloat16* __restrict__ Vt,
    __hip_bfloat16* __restrict__ attn) {
  __shared__ __hip_bfloat16 lK[2][64][64];    // [buf][sk][d]  f-swizzled, dbuf
  __shared__ __hip_bfloat16 lV[2][64][64];    // [buf][d][sk]  XOR-swizzled, dbuf
  __shared__ __hip_bfloat16 lO[4][16][64];    // per-wave epilogue transpose
  const int t = threadIdx.x;
  const int lane = t & 63, w = t >> 6;
  const int quad = lane >> 4, ln = lane & 15;
  const int id = blockIdx.x;
  const int bh = id & 31;                     // fast index -> XCD spread
  const int j = id >> 5;                      // 0..31
  const int k2 = j >> 3, g = j & 7;
  const int qt = 8 * k2 + ((k2 & 1) ? (7 - g) : g);   // balanced qt perm
  const int q0 = qt * 64;
  const size_t base = (size_t)bh * 2048 * 64;
  const __hip_bfloat16* Kb = K + base;
  const __hip_bfloat16* Vb = Vt + base;
  const int b = bh >> 4, h = bh & 15;

  const int srow = lane >> 3;
  const int schunkV = ((lane & 7) ^ srow) * 8;            // V: f(r) = r&7
  const int rb0 = w * 16;
  const int sig_base = (ln >> 2) * 8 + (ln & 3);

  #pragma unroll
  for (int g2 = 0; g2 < 2; ++g2) {
    const int rbase = rb0 + g2 * 8;
    const int schunkK = (((lane & 7) ^ srow) ^ (g2 << 2)) * 8;  // f-bit2 = g2
    __builtin_amdgcn_global_load_lds(
        (const __attribute__((address_space(1))) void*)
            (Kb + (size_t)(rbase + srow) * 64 + schunkK),
        (__attribute__((address_space(3))) void*)&lK[0][rbase][0], 16, 0, 0);
    __builtin_amdgcn_global_load_lds(
        (const __attribute__((address_space(1))) void*)
            (Vb + (size_t)(rbase + srow) * 2048 + schunkV),
        (__attribute__((address_space(3))) void*)&lV[0][rbase][0], 16, 0, 0);
  }

  // qf: raw qkv q-slice + fused RoPE (scale = (1/8)*log2(e) for exp2-softmax)
  short8 qf[2];
  {
    const float qs = 0.125f * 1.44269504088896340736f;
    const int s = q0 + w * 16 + ln;
    const size_t qrow = (size_t)(b * 2048 + s) * 3072 + h * 64;
    short8 raw0 = *(const short8*)&qkv[qrow + quad * 8];
    short8 raw1 = *(const short8*)&qkv[qrow + 32 + quad * 8];
    const float4 ta = *(const float4*)&tab[(size_t)s * 32 + quad * 4];
    const float4 tb = *(const float4*)&tab[(size_t)s * 32 + quad * 4 + 2];
    const float4 tc = *(const float4*)&tab[(size_t)s * 32 + 16 + quad * 4];
    const float4 td = *(const float4*)&tab[(size_t)s * 32 + 16 + quad * 4 + 2];
    qf[0] = rope8(raw0, ta, tb, qs);
    qf[1] = rope8(raw1, tc, td, qs);
  }

  float4v acc_o[4];
  #pragma unroll
  for (int dt = 0; dt < 4; ++dt) acc_o[dt] = (float4v){0.f, 0.f, 0.f, 0.f};
  float suml = 0.f;

  for (int kt = 0; kt <= qt; ++kt) {
    const int buf = kt & 1;
    __syncthreads();

    if (kt < qt) {
      #pragma unroll
      for (int g2 = 0; g2 < 2; ++g2) {
        const int rbase = rb0 + g2 * 8;
        const int schunkK = (((lane & 7) ^ srow) ^ (g2 << 2)) * 8;
        __builtin_amdgcn_global_load_lds(
            (const __attribute__((address_space(1))) void*)
                (Kb + (size_t)((kt + 1) * 64 + rbase + srow) * 64 + schunkK),
            (__attribute__((address_space(3))) void*)&lK[buf ^ 1][rbase][0], 16, 0, 0);
        __builtin_amdgcn_global_load_lds(
            (const __attribute__((address_space(1))) void*)
                (Vb + (size_t)(rbase + srow) * 2048 + (kt + 1) * 64 + schunkV),
            (__attribute__((address_space(3))) void*)&lV[buf ^ 1][rbase][0], 16, 0, 0);
      }
    }

    float4v s4[4];
    #pragma unroll
    for (int nt = 0; nt < 4; ++nt) {
      const int krow = sig_base + ((nt & 1) << 2) + ((nt >> 1) << 5);
      const int k7 = (krow & 7) ^ (((krow >> 3) & 1) << 2);   // f(krow)
      float4v a = (float4v){0.f, 0.f, 0.f, 0.f};
      #pragma unroll
      for (int step = 0; step < 2; ++step) {
        short8 kf = *(const short8*)&lK[buf][krow][((step * 4 + quad) ^ k7) * 8];
        a = __builtin_amdgcn_mfma_f32_16x16x32_bf16(kf, qf[step], a, 0, 0, 0);
      }
      s4[nt] = a;
    }
    if (kt == qt) {
      const int qr = q0 + w * 16 + ln;
      #pragma unroll
      for (int nt = 0; nt < 4; ++nt)
        #pragma unroll
        for (int r = 0; r < 4; ++r) {
          const int kglob = kt * 64 + quad * 8 + ((nt & 1) << 2) + r + ((nt >> 1) << 5);
          if (kglob > qr) s4[nt][r] = -64.f;
        }
    }
    #pragma unroll
    for (int nt = 0; nt < 4; ++nt)
      #pragma unroll
      for (int r = 0; r < 4; ++r) {
        s4[nt][r] = __builtin_amdgcn_exp2f(s4[nt][r]);
        suml += s4[nt][r];
      }
    #pragma unroll
    for (int s = 0; s < 2; ++s) {
      union { short8 v; short e[8]; } pb;
      #pragma unroll
      for (int i = 0; i < 4; ++i) {
        __hip_bfloat16 b0 = __float2bfloat16(s4[2 * s][i]);
        __hip_bfloat16 b1 = __float2bfloat16(s4[2 * s + 1][i]);
        pb.e[i] = *reinterpret_cast<short*>(&b0);
        pb.e[4 + i] = *reinterpret_cast<short*>(&b1);
      }
      #pragma unroll
      for (int dt = 0; dt < 4; ++dt) {
        short8 vf = *(const short8*)&lV[buf][dt * 16 + ln][((s * 4 + quad) ^ (ln & 7)) * 8];
        acc_o[dt] = __builtin_amdgcn_mfma_f32_16x16x32_bf16(vf, pb.v, acc_o[dt], 0, 0, 0);
      }
    }
  }

  float l0 = suml + __shfl_xor(suml, 16);
  const float inv = 1.0f / (l0 + __shfl_xor(l0, 32));

  #pragma unroll
  for (int dt = 0; dt < 4; ++dt) {
    union { uint2 u; short e[4]; } pk;
    #pragma unroll
    for (int r = 0; r < 4; ++r) {
      __hip_bfloat16 bv = __float2bfloat16(acc_o[dt][r] * inv);
      pk.e[r] = *reinterpret_cast<short*>(&bv);
    }
    *(uint2*)&lO[w][ln][dt * 16 + quad * 4] = pk.u;
  }

  const int orow = lane >> 2;           // q' 0..15
  const int od = (lane & 3) * 16;       // d base (16 elems = 32B per lane)
  const uint4 w0 = *(const uint4*)&lO[w][orow][od];
  const uint4 w1 = *(const uint4*)&lO[w][orow][od + 8];
  const size_t rg = (size_t)(b * 2048 + q0 + w * 16 + orow);
  *(uint4*)&attn[rg * 1024 + h * 64 + od] = w0;
  *(uint4*)&attn[rg * 1024 + h * 64 + od + 8] = w1;
}

// ---------------------------------------------------------------------------
extern "C" void kernel_launch(void* const* d_in, const int* in_sizes, int n_in,
                              void* d_out, int out_size, void* d_ws, size_t ws_size,
                              hipStream_t stream) {
  const float* x    = (const float*)d_in[0];  // (2,2048,1024) fp32
  const float* Wqkv = (const float*)d_in[1];  // (1024,3072)   fp32
  const float* Wout = (const float*)d_in[2];  // (1024,1024)   fp32
  float* out = (float*)d_out;                 // (2,2048,1024) fp32

  __hip_bfloat16* ws = (__hip_bfloat16*)d_ws;
  __hip_bfloat16* xb    = ws;                          // 4096*1024
  __hip_bfloat16* WqkvT = xb    + (size_t)4096 * 1024; // 3072*1024
  __hip_bfloat16* WoutT = WqkvT + (size_t)3072 * 1024; // 1024*1024
  __hip_bfloat16* qkv   = WoutT + (size_t)1024 * 1024; // 4096*3072
  __hip_bfloat16* Q     = qkv   + (size_t)4096 * 3072; // slot unused (r25)
  __hip_bfloat16* K     = Q     + (size_t)32 * 2048 * 64;
  __hip_bfloat16* Vt    = K     + (size_t)32 * 2048 * 64;
  __hip_bfloat16* attn  = Vt    + (size_t)32 * 2048 * 64;  // dedicated
  float2*         tab   = (float2*)(attn + (size_t)4096 * 1024);  // 2048x32

  prep_all<<<8448, 256, 0, stream>>>(x, xb, tab, Wqkv, Wout, WqkvT, WoutT);
  gemm1_8p<<<dim3(3072 / 256, 4096 / 256), 512, 0, stream>>>(xb, WqkvT, qkv);
  qkv_prep<<<dim3(32, 32), 256, 0, stream>>>(qkv, tab, K, Vt);
  attention<<<1024, 256, 0, stream>>>(qkv, tab, K, Vt, attn);
  gemm_bt<float, 128, 64><<<dim3(1024 / 64, 4096 / 128), 256, 0, stream>>>(attn, WoutT, out, 4096, 1024, 1024);
}

// Round 12
// 174.084 us; speedup vs baseline: 1.0849x; 1.0849x over previous
//
#include <hip/hip_runtime.h>
#include <hip/hip_bf16.h>

typedef __attribute__((ext_vector_type(8))) short short8;     // 8 bf16 (MFMA A/B frag, K=32)
typedef __attribute__((ext_vector_type(4))) float float4v;    // MFMA C/D frag

// RoPE on an 8-elem bf16 chunk (4 pairs). tA/tB = tab[p..p+1], tab[p+2..p+3]
// as (cos,sin,cos,sin). Identical rounding chain to the old qkv_prep path.
__device__ inline short8 rope8(short8 raw, float4 tA, float4 tB, float scale) {
  float c[4] = {tA.x, tA.z, tB.x, tB.z};
  float s[4] = {tA.y, tA.w, tB.y, tB.w};
  union { short8 v; short e[8]; } in, out;
  in.v = raw;
  #pragma unroll
  for (int j = 0; j < 4; ++j) {
    __hip_bfloat16 h1 = *reinterpret_cast<__hip_bfloat16*>(&in.e[2 * j]);
    __hip_bfloat16 h2 = *reinterpret_cast<__hip_bfloat16*>(&in.e[2 * j + 1]);
    const float x1 = __bfloat162float(h1), x2 = __bfloat162float(h2);
    __hip_bfloat16 o1 = __float2bfloat16((x1 * c[j] - x2 * s[j]) * scale);
    __hip_bfloat16 o2 = __float2bfloat16((x1 * s[j] + x2 * c[j]) * scale);
    out.e[2 * j]     = *reinterpret_cast<short*>(&o1);
    out.e[2 * j + 1] = *reinterpret_cast<short*>(&o2);
  }
  return out.v;
}

// ---------------------------------------------------------------------------
// prep_all: all input prep in ONE launch.
//   blocks [0,4096):     x fp32 -> xb bf16 (float4 vectorized)
//   blocks [4096,4352):  RoPE table tab[s][p] = (cos,sin), 512 KB, L2-resident
//   blocks [4352,7424):  Wqkv (1024x3072) -> WqkvT (3072x1024) bf16 transpose
//   blocks [7424,8448):  Wout (1024x1024) -> WoutT transpose
// r27: transpose LOAD phase vectorized to one float4/thread (was 4 scalar
// loads); packed 4B stores kept from r25.
// ---------------------------------------------------------------------------
__global__ __launch_bounds__(256) void prep_all(
    const float* __restrict__ x, __hip_bfloat16* __restrict__ xb,
    float2* __restrict__ tab,
    const float* __restrict__ Wqkv, const float* __restrict__ Wout,
    __hip_bfloat16* __restrict__ WqkvT, __hip_bfloat16* __restrict__ WoutT) {
  __shared__ __hip_bfloat16 tile[32][33];
  const int id = blockIdx.x;
  if (id < 4096) {
    const int i = id * 256 + threadIdx.x;
    const float4 v = *(const float4*)(x + (size_t)i * 4);
    __hip_bfloat16 o[4];
    o[0] = __float2bfloat16(v.x); o[1] = __float2bfloat16(v.y);
    o[2] = __float2bfloat16(v.z); o[3] = __float2bfloat16(v.w);
    *(uint2*)(xb + (size_t)i * 4) = *(const uint2*)o;
    return;
  }
  if (id < 4352) {
    const int i = (id - 4096) * 256 + threadIdx.x;   // 65536
    const int s = i >> 5, p = i & 31;
    const float freq = powf(10000.f, -(float)(p * 2) / 64.f);
    float sn, cs;
    sincosf((float)s * freq, &sn, &cs);
    tab[i] = make_float2(cs, sn);
    return;
  }
  const float* in;
  __hip_bfloat16* out;
  int C, bx, by;
  if (id < 7424) {
    const int lid = id - 4352;
    in = Wqkv; out = WqkvT; C = 3072; bx = lid % 96; by = lid / 96;
  } else {
    const int lid = id - 7424;
    in = Wout; out = WoutT; C = 1024; bx = lid & 31; by = lid >> 5;
  }
  const int R = 1024;
  const int c0 = bx * 32, r0 = by * 32;
  // load: one float4 (4 cols) per thread -> full 32x32 tile in one shot
  const int row = threadIdx.x >> 3;           // 0..31
  const int cg  = (threadIdx.x & 7) * 4;      // 0,4,...,28
  {
    const float4 v = *(const float4*)&in[(size_t)(r0 + row) * C + (c0 + cg)];
    tile[row][cg]     = __float2bfloat16(v.x);
    tile[row][cg + 1] = __float2bfloat16(v.y);
    tile[row][cg + 2] = __float2bfloat16(v.z);
    tile[row][cg + 3] = __float2bfloat16(v.w);
  }
  __syncthreads();
  // packed store: lane owns row-pair (2sx, 2sx+1) at col i -> one 4B store
  const int sx = threadIdx.x & 15, sy = threadIdx.x >> 4;  // sy 0..15
  #pragma unroll
  for (int i = sy; i < 32; i += 16) {
    union { unsigned u; short e[2]; } pk;
    pk.e[0] = *reinterpret_cast<short*>(&tile[2 * sx][i]);
    pk.e[1] = *reinterpret_cast<short*>(&tile[2 * sx + 1][i]);
    *(unsigned*)&out[(size_t)(c0 + i) * R + r0 + 2 * sx] = pk.u;
  }
}

// ---------------------------------------------------------------------------
// gemm_bt: C (MxN, OutT) = A (MxK, row-major bf16) @ Bt^T  (Bt is NxK bf16)
// r6/r12 measured-optimum 2-barrier structure. gemm1 pipelining is CLOSED:
// r22 (coarse ring, 46us) and r26 (4-phase counted-vmcnt, 60us) both lose
// to this 40us form — 256^2 tiles give 192 blocks < 256 CUs at 1 block/CU,
// so every barrier is a convoy stall no co-resident block can fill.
// gemm1: <bf16,128,128> (768 blocks); gemm2: <float,128,64> (512 blocks).
// ---------------------------------------------------------------------------
template <typename OutT, int BM, int BN>
__global__ __launch_bounds__(256) void gemm_bt(
    const __hip_bfloat16* __restrict__ A,
    const __hip_bfloat16* __restrict__ Bt,
    OutT* __restrict__ C,
    int M, int N, int K) {
  __shared__ __hip_bfloat16 lA[BM][64];
  __shared__ __hip_bfloat16 lB[BN][64];
  constexpr int NI = BM / 32, NJ = BN / 32;
  const int t = threadIdx.x;
  const int lane = t & 63, wave = t >> 6;
  const int quad = lane >> 4, ln = lane & 15;
  const int m0 = blockIdx.y * BM, n0 = blockIdx.x * BN;
  const int wm = (wave >> 1) * (BM / 2), wn = (wave & 1) * (BN / 2);
  const int srow = lane >> 3;
  const int schunk = ((lane & 7) ^ srow) * 8;

  float4v acc[NI][NJ];
  #pragma unroll
  for (int i = 0; i < NI; ++i)
    #pragma unroll
    for (int j = 0; j < NJ; ++j)
      acc[i][j] = (float4v){0.f, 0.f, 0.f, 0.f};

  for (int kt = 0; kt < K; kt += 64) {
    __syncthreads();
    #pragma unroll
    for (int g = 0; g < BM / 32; ++g) {
      const int rbase = wave * (BM / 4) + g * 8;
      __builtin_amdgcn_global_load_lds(
          (const __attribute__((address_space(1))) void*)
              (A + (size_t)(m0 + rbase + srow) * K + kt + schunk),
          (__attribute__((address_space(3))) void*)&lA[rbase][0], 16, 0, 0);
    }
    #pragma unroll
    for (int g = 0; g < BN / 32; ++g) {
      const int rbase = wave * (BN / 4) + g * 8;
      __builtin_amdgcn_global_load_lds(
          (const __attribute__((address_space(1))) void*)
              (Bt + (size_t)(n0 + rbase + srow) * K + kt + schunk),
          (__attribute__((address_space(3))) void*)&lB[rbase][0], 16, 0, 0);
    }
    __syncthreads();
    #pragma unroll
    for (int step = 0; step < 2; ++step) {
      short8 af[NI], bf[NJ];
      #pragma unroll
      for (int i = 0; i < NI; ++i)
        af[i] = *(const short8*)&lA[wm + i * 16 + ln][((step * 4 + quad) ^ (ln & 7)) * 8];
      #pragma unroll
      for (int j = 0; j < NJ; ++j)
        bf[j] = *(const short8*)&lB[wn + j * 16 + ln][((step * 4 + quad) ^ (ln & 7)) * 8];
      #pragma unroll
      for (int i = 0; i < NI; ++i)
        #pragma unroll
        for (int j = 0; j < NJ; ++j)
          acc[i][j] = __builtin_amdgcn_mfma_f32_16x16x32_bf16(af[i], bf[j], acc[i][j], 0, 0, 0);
    }
  }
  #pragma unroll
  for (int i = 0; i < NI; ++i)
    #pragma unroll
    for (int j = 0; j < NJ; ++j)
      #pragma unroll
      for (int r = 0; r < 4; ++r) {
        const int row = m0 + wm + i * 16 + quad * 4 + r;
        const int col = n0 + wn + j * 16 + ln;
        if constexpr (__is_same(OutT, float))
          C[(size_t)row * N + col] = acc[i][j][r];
        else
          C[(size_t)row * N + col] = __float2bfloat16(acc[i][j][r]);
      }
}

// ---------------------------------------------------------------------------
// qkv_prep r25: K RoPE (vectorized 16B) + V transpose (8B both sides).
// Q dropped — attention fuses RoPE-Q into its one-time qf load.
// ---------------------------------------------------------------------------
__global__ __launch_bounds__(256) void qkv_prep(
    const __hip_bfloat16* __restrict__ qkv,
    const float2* __restrict__ tab,
    __hip_bfloat16* __restrict__ K,
    __hip_bfloat16* __restrict__ Vt) {
  __shared__ __hip_bfloat16 tile[64][68];     // +4 pad: 8B-aligned rows
  const int s0 = blockIdx.x * 64;
  const int bh = blockIdx.y;
  const int h = bh & 15, b = bh >> 4;
  const int t = threadIdx.x;

  const int dd = (t & 7) * 8;
  const int sl = t >> 3;                      // 0..31
  #pragma unroll
  for (int ss = sl; ss < 64; ss += 32) {
    const int s = s0 + ss;
    short8 kv = *(const short8*)&qkv[(size_t)(b * 2048 + s) * 3072 + 1024 + h * 64 + dd];
    const float4 tA = *(const float4*)&tab[(size_t)s * 32 + (dd >> 1)];
    const float4 tB = *(const float4*)&tab[(size_t)s * 32 + (dd >> 1) + 2];
    *(short8*)&K[((size_t)bh * 2048 + s) * 64 + dd] = rope8(kv, tA, tB, 1.0f);
  }

  const int dgrp = (t & 15) * 4;              // d base for load
  const int srow = t >> 4;                    // 0..15
  #pragma unroll
  for (int i = srow; i < 64; i += 16) {
    ushort4 v4 = *(const ushort4*)&qkv[(size_t)(b * 2048 + s0 + i) * 3072 + 2048 + h * 64 + dgrp];
    *(ushort4*)&tile[i][dgrp] = v4;
  }
  __syncthreads();
  const int vx = t & 15, vy = t >> 4;         // vx -> s-quad, vy -> d
  #pragma unroll
  for (int d = vy; d < 64; d += 16) {
    union { ushort4 v; short e[4]; } pk;
    #pragma unroll
    for (int jj = 0; jj < 4; ++jj)
      pk.e[jj] = *reinterpret_cast<short*>(&tile[4 * vx + jj][d]);
    *(ushort4*)&Vt[((size_t)bh * 64 + d) * 2048 + s0 + 4 * vx] = pk.v;
  }
}

// ---------------------------------------------------------------------------
// Flash-style causal attention — r25 form (swapped-operand QK, in-register P,
// f-swizzle lK, fused RoPE-Q, packed lO epilogue). Unchanged.
// ---------------------------------------------------------------------------
__global__ __launch_bounds__(256) void attention(
    const __hip_bfloat16* __restrict__ qkv,
    const float2* __restrict__ tab,
    const __hip_bfloat16* __restrict__ K,
    const __hip_bfloat16* __restrict__ Vt,
    __hip_bfloat16* __restrict__ attn) {
  __shared__ __hip_bfloat16 lK[2][64][64];    // [buf][sk][d]  f-swizzled, dbuf
  __shared__ __hip_bfloat16 lV[2][64][64];    // [buf][d][sk]  XOR-swizzled, dbuf
  __shared__ __hip_bfloat16 lO[4][16][64];    // per-wave epilogue transpose
  const int t = threadIdx.x;
  const int lane = t & 63, w = t >> 6;
  const int quad = lane >> 4, ln = lane & 15;
  const int id = blockIdx.x;
  const int bh = id & 31;                     // fast index -> XCD spread
  const int j = id >> 5;                      // 0..31
  const int k2 = j >> 3, g = j & 7;
  const int qt = 8 * k2 + ((k2 & 1) ? (7 - g) : g);   // balanced qt perm
  const int q0 = qt * 64;
  const size_t base = (size_t)bh * 2048 * 64;
  const __hip_bfloat16* Kb = K + base;
  const __hip_bfloat16* Vb = Vt + base;
  const int b = bh >> 4, h = bh & 15;

  const int srow = lane >> 3;
  const int schunkV = ((lane & 7) ^ srow) * 8;            // V: f(r) = r&7
  const int rb0 = w * 16;
  const int sig_base = (ln >> 2) * 8 + (ln & 3);

  #pragma unroll
  for (int g2 = 0; g2 < 2; ++g2) {
    const int rbase = rb0 + g2 * 8;
    const int schunkK = (((lane & 7) ^ srow) ^ (g2 << 2)) * 8;  // f-bit2 = g2
    __builtin_amdgcn_global_load_lds(
        (const __attribute__((address_space(1))) void*)
            (Kb + (size_t)(rbase + srow) * 64 + schunkK),
        (__attribute__((address_space(3))) void*)&lK[0][rbase][0], 16, 0, 0);
    __builtin_amdgcn_global_load_lds(
        (const __attribute__((address_space(1))) void*)
            (Vb + (size_t)(rbase + srow) * 2048 + schunkV),
        (__attribute__((address_space(3))) void*)&lV[0][rbase][0], 16, 0, 0);
  }

  // qf: raw qkv q-slice + fused RoPE (scale = (1/8)*log2(e) for exp2-softmax)
  short8 qf[2];
  {
    const float qs = 0.125f * 1.44269504088896340736f;
    const int s = q0 + w * 16 + ln;
    const size_t qrow = (size_t)(b * 2048 + s) * 3072 + h * 64;
    short8 raw0 = *(const short8*)&qkv[qrow + quad * 8];
    short8 raw1 = *(const short8*)&qkv[qrow + 32 + quad * 8];
    const float4 ta = *(const float4*)&tab[(size_t)s * 32 + quad * 4];
    const float4 tb = *(const float4*)&tab[(size_t)s * 32 + quad * 4 + 2];
    const float4 tc = *(const float4*)&tab[(size_t)s * 32 + 16 + quad * 4];
    const float4 td = *(const float4*)&tab[(size_t)s * 32 + 16 + quad * 4 + 2];
    qf[0] = rope8(raw0, ta, tb, qs);
    qf[1] = rope8(raw1, tc, td, qs);
  }

  float4v acc_o[4];
  #pragma unroll
  for (int dt = 0; dt < 4; ++dt) acc_o[dt] = (float4v){0.f, 0.f, 0.f, 0.f};
  float suml = 0.f;

  for (int kt = 0; kt <= qt; ++kt) {
    const int buf = kt & 1;
    __syncthreads();   // drains K[kt]/V[kt] DMA (issued a full iter ago);
                       // prev iter's buf^1 reads are all before this point

    if (kt < qt) {
      #pragma unroll
      for (int g2 = 0; g2 < 2; ++g2) {
        const int rbase = rb0 + g2 * 8;
        const int schunkK = (((lane & 7) ^ srow) ^ (g2 << 2)) * 8;
        __builtin_amdgcn_global_load_lds(
            (const __attribute__((address_space(1))) void*)
                (Kb + (size_t)((kt + 1) * 64 + rbase + srow) * 64 + schunkK),
            (__attribute__((address_space(3))) void*)&lK[buf ^ 1][rbase][0], 16, 0, 0);
        __builtin_amdgcn_global_load_lds(
            (const __attribute__((address_space(1))) void*)
                (Vb + (size_t)(rbase + srow) * 2048 + (kt + 1) * 64 + schunkV),
            (__attribute__((address_space(3))) void*)&lV[buf ^ 1][rbase][0], 16, 0, 0);
      }
    }

    // QK^T swapped: s4[nt] lane(quad,ln) reg r = P[sigma(nt,quad*4+r)][q=ln]
    float4v s4[4];
    #pragma unroll
    for (int nt = 0; nt < 4; ++nt) {
      const int krow = sig_base + ((nt & 1) << 2) + ((nt >> 1) << 5);
      const int k7 = (krow & 7) ^ (((krow >> 3) & 1) << 2);   // f(krow)
      float4v a = (float4v){0.f, 0.f, 0.f, 0.f};
      #pragma unroll
      for (int step = 0; step < 2; ++step) {
        short8 kf = *(const short8*)&lK[buf][krow][((step * 4 + quad) ^ k7) * 8];
        a = __builtin_amdgcn_mfma_f32_16x16x32_bf16(kf, qf[step], a, 0, 0, 0);
      }
      s4[nt] = a;
    }
    if (kt == qt) {
      const int qr = q0 + w * 16 + ln;
      #pragma unroll
      for (int nt = 0; nt < 4; ++nt)
        #pragma unroll
        for (int r = 0; r < 4; ++r) {
          const int kglob = kt * 64 + quad * 8 + ((nt & 1) << 2) + r + ((nt >> 1) << 5);
          if (kglob > qr) s4[nt][r] = -64.f;
        }
    }
    // exp (bare v_exp_f32) + row-sum contribution
    #pragma unroll
    for (int nt = 0; nt < 4; ++nt)
      #pragma unroll
      for (int r = 0; r < 4; ++r) {
        s4[nt][r] = __builtin_amdgcn_exp2f(s4[nt][r]);
        suml += s4[nt][r];
      }
    // PV: B-frag step s = lane-local pack of s4[2s][0..3], s4[2s+1][0..3]
    #pragma unroll
    for (int s = 0; s < 2; ++s) {
      union { short8 v; short e[8]; } pb;
      #pragma unroll
      for (int i = 0; i < 4; ++i) {
        __hip_bfloat16 b0 = __float2bfloat16(s4[2 * s][i]);
        __hip_bfloat16 b1 = __float2bfloat16(s4[2 * s + 1][i]);
        pb.e[i] = *reinterpret_cast<short*>(&b0);
        pb.e[4 + i] = *reinterpret_cast<short*>(&b1);
      }
      #pragma unroll
      for (int dt = 0; dt < 4; ++dt) {
        short8 vf = *(const short8*)&lV[buf][dt * 16 + ln][((s * 4 + quad) ^ (ln & 7)) * 8];
        acc_o[dt] = __builtin_amdgcn_mfma_f32_16x16x32_bf16(vf, pb.v, acc_o[dt], 0, 0, 0);
      }
    }
  }

  // l[q] = sum over the 4 quads holding q=ln's P-columns
  float l0 = suml + __shfl_xor(suml, 16);
  const float inv = 1.0f / (l0 + __shfl_xor(l0, 32));

  // Epilogue: lane holds O^T[d=dt*16+quad*4+r][q=ln]; transpose via per-wave
  // LDS tile; packed 8B writes (r-values contiguous in lO's col dim).
  #pragma unroll
  for (int dt = 0; dt < 4; ++dt) {
    union { uint2 u; short e[4]; } pk;
    #pragma unroll
    for (int r = 0; r < 4; ++r) {
      __hip_bfloat16 bv = __float2bfloat16(acc_o[dt][r] * inv);
      pk.e[r] = *reinterpret_cast<short*>(&bv);
    }
    *(uint2*)&lO[w][ln][dt * 16 + quad * 4] = pk.u;
  }

  const int orow = lane >> 2;           // q' 0..15
  const int od = (lane & 3) * 16;       // d base (16 elems = 32B per lane)
  const uint4 w0 = *(const uint4*)&lO[w][orow][od];
  const uint4 w1 = *(const uint4*)&lO[w][orow][od + 8];
  const size_t rg = (size_t)(b * 2048 + q0 + w * 16 + orow);
  *(uint4*)&attn[rg * 1024 + h * 64 + od] = w0;
  *(uint4*)&attn[rg * 1024 + h * 64 + od + 8] = w1;
}

// ---------------------------------------------------------------------------
extern "C" void kernel_launch(void* const* d_in, const int* in_sizes, int n_in,
                              void* d_out, int out_size, void* d_ws, size_t ws_size,
                              hipStream_t stream) {
  const float* x    = (const float*)d_in[0];  // (2,2048,1024) fp32
  const float* Wqkv = (const float*)d_in[1];  // (1024,3072)   fp32
  const float* Wout = (const float*)d_in[2];  // (1024,1024)   fp32
  float* out = (float*)d_out;                 // (2,2048,1024) fp32

  __hip_bfloat16* ws = (__hip_bfloat16*)d_ws;
  __hip_bfloat16* xb    = ws;                          // 4096*1024
  __hip_bfloat16* WqkvT = xb    + (size_t)4096 * 1024; // 3072*1024
  __hip_bfloat16* WoutT = WqkvT + (size_t)3072 * 1024; // 1024*1024
  __hip_bfloat16* qkv   = WoutT + (size_t)1024 * 1024; // 4096*3072
  __hip_bfloat16* Q     = qkv   + (size_t)4096 * 3072; // slot unused (r25)
  __hip_bfloat16* K     = Q     + (size_t)32 * 2048 * 64;
  __hip_bfloat16* Vt    = K     + (size_t)32 * 2048 * 64;
  __hip_bfloat16* attn  = Vt    + (size_t)32 * 2048 * 64;  // dedicated
  float2*         tab   = (float2*)(attn + (size_t)4096 * 1024);  // 2048x32

  prep_all<<<8448, 256, 0, stream>>>(x, xb, tab, Wqkv, Wout, WqkvT, WoutT);
  gemm_bt<__hip_bfloat16, 128, 128><<<dim3(3072 / 128, 4096 / 128), 256, 0, stream>>>(xb, WqkvT, qkv, 4096, 3072, 1024);
  qkv_prep<<<dim3(32, 32), 256, 0, stream>>>(qkv, tab, K, Vt);
  attention<<<1024, 256, 0, stream>>>(qkv, tab, K, Vt, attn);
  gemm_bt<float, 128, 64><<<dim3(1024 / 64, 4096 / 128), 256, 0, stream>>>(attn, WoutT, out, 4096, 1024, 1024);
}